// Round 1
// baseline (357.328 us; speedup 1.0000x reference)
//
#include <hip/hip_runtime.h>

#define A_N 100000
#define B_N 8
#define C_N 80
#define M_N 32

// ws layout (floats): [0..7] clsSum, [8..15] regSum, [16..23] numPos
__global__ __launch_bounds__(256) void focal_main(
    const float* __restrict__ cls,     // [B,A,C]
    const float* __restrict__ regs,    // [B,A,4]
    const float* __restrict__ anchors, // [A,4] (leading 1 dim dropped)
    const float* __restrict__ ann,     // [B,M,5]
    float* __restrict__ ws)
{
    __shared__ float sAnn[M_N * 5];
    __shared__ int   sMeta[256];

    const int b   = blockIdx.y;
    const int s   = blockIdx.x * 256;
    const int tid = threadIdx.x;

    if (tid < M_N * 5) sAnn[tid] = ann[b * M_N * 5 + tid];
    __syncthreads();

    float regPart  = 0.f;
    float nposPart = 0.f;

    const int a = s + tid;
    int meta = -2;  // -2 = ignore/skip, -1 = negative, >=0 = positive class id
    if (a < A_N) {
        float4 an = reinterpret_cast<const float4*>(anchors)[a];
        float areaA = (an.z - an.x) * (an.w - an.y);
        float best = -1e30f;
        int bestIdx = 0;
        #pragma unroll
        for (int m = 0; m < M_N; ++m) {
            float gx1 = sAnn[m*5+0], gy1 = sAnn[m*5+1];
            float gx2 = sAnn[m*5+2], gy2 = sAnn[m*5+3];
            float gl  = sAnn[m*5+4];
            float iouv;
            if (gl >= 0.f) {
                float areaB = (gx2 - gx1) * (gy2 - gy1);
                float iw = fmaxf(fminf(an.z, gx2) - fmaxf(an.x, gx1), 0.f);
                float ih = fmaxf(fminf(an.w, gy2) - fmaxf(an.y, gy1), 0.f);
                float inter = iw * ih;
                float ua = fmaxf(areaA + areaB - inter, 1e-8f);
                iouv = inter / ua;
            } else {
                iouv = -1.f;
            }
            if (iouv > best) { best = iouv; bestIdx = m; }  // strict > keeps first max (argmax semantics)
        }
        bool pos = best >= 0.5f;
        bool neg = best <  0.4f;
        meta = pos ? (int)sAnn[bestIdx*5+4] : (neg ? -1 : -2);
        if (pos) {
            nposPart = 1.f;
            float4 rg = reinterpret_cast<const float4*>(regs)[(size_t)b * A_N + a];
            float gx1 = sAnn[bestIdx*5+0], gy1 = sAnn[bestIdx*5+1];
            float gx2 = sAnn[bestIdx*5+2], gy2 = sAnn[bestIdx*5+3];
            float aw = an.z - an.x, ah = an.w - an.y;
            float acx = an.x + 0.5f * aw, acy = an.y + 0.5f * ah;
            float gw0 = gx2 - gx1, gh0 = gy2 - gy1;
            float gcx = gx1 + 0.5f * gw0, gcy = gy1 + 0.5f * gh0;
            float gw = fmaxf(gw0, 1.f), gh = fmaxf(gh0, 1.f);
            float t0 = ((gcx - acx) / aw) * 10.f;
            float t1 = ((gcy - acy) / ah) * 10.f;
            float t2 = __logf(gw / aw) * 5.f;
            float t3 = __logf(gh / ah) * 5.f;
            float d0 = fabsf(t0 - rg.x), d1 = fabsf(t1 - rg.y);
            float d2 = fabsf(t2 - rg.z), d3 = fabsf(t3 - rg.w);
            #define SL1(d) ((d) <= (1.f/9.f) ? 4.5f*(d)*(d) : (d) - (0.5f/9.f))
            regPart = SL1(d0) + SL1(d1) + SL1(d2) + SL1(d3);
            #undef SL1
        }
    }
    sMeta[tid] = meta;
    __syncthreads();

    // Phase B: stream this block's [nAnch,80] cls slab, coalesced float4
    const int nAnch  = min(256, A_N - s);
    const int elems4 = nAnch * (C_N / 4);
    const float4* cls4 = reinterpret_cast<const float4*>(cls + ((size_t)b * A_N + s) * C_N);
    float clsPart = 0.f;
    for (int i = tid; i < elems4; i += 256) {
        float4 v = cls4[i];
        int al = i / 20;              // local anchor
        int c0 = (i - al * 20) * 4;   // first class of this float4
        int m  = sMeta[al];
        if (m == -2) continue;        // ignore band: no contribution
        float pv[4] = {v.x, v.y, v.z, v.w};
        #pragma unroll
        for (int j = 0; j < 4; ++j) {
            float p = fminf(fmaxf(pv[j], 1e-4f), 1.f - 1e-4f);
            bool hit = (m == c0 + j);                       // target==1 element
            float q = hit ? p : (1.f - p);                  // log argument
            float f = hit ? 0.25f * (1.f - p) * (1.f - p)
                          : 0.75f * p * p;                  // alpha * (..)^gamma
            clsPart += f * (-__logf(q));
        }
    }

    // wave reduce (64 lanes) + one atomic per wave
    #pragma unroll
    for (int off = 32; off > 0; off >>= 1) {
        clsPart  += __shfl_down(clsPart,  off);
        regPart  += __shfl_down(regPart,  off);
        nposPart += __shfl_down(nposPart, off);
    }
    if ((tid & 63) == 0) {
        atomicAdd(&ws[b],      clsPart);
        atomicAdd(&ws[8 + b],  regPart);
        atomicAdd(&ws[16 + b], nposPart);
    }
}

__global__ void focal_final(const float* __restrict__ ann,
                            const float* __restrict__ ws,
                            float* __restrict__ out)
{
    if (threadIdx.x == 0 && blockIdx.x == 0) {
        float cSum = 0.f, rSum = 0.f;
        for (int b = 0; b < B_N; ++b) {
            bool anyv = false;
            for (int m = 0; m < M_N; ++m)
                anyv = anyv || (ann[b * M_N * 5 + m * 5 + 4] >= 0.f);
            float np = ws[16 + b];
            float cl = ws[b] / fmaxf(np, 1.f);
            float rl = ws[8 + b] / fmaxf(4.f * np, 1.f);
            if (np <= 0.f) rl = 0.f;
            if (!anyv) { cl = 0.f; rl = 0.f; }
            cSum += cl;
            rSum += rl;
        }
        out[0] = cSum / (float)B_N;
        out[1] = rSum / (float)B_N;
    }
}

extern "C" void kernel_launch(void* const* d_in, const int* in_sizes, int n_in,
                              void* d_out, int out_size, void* d_ws, size_t ws_size,
                              hipStream_t stream) {
    const float* cls     = (const float*)d_in[0];
    const float* regs    = (const float*)d_in[1];
    const float* anchors = (const float*)d_in[2];
    const float* ann     = (const float*)d_in[3];
    float* out = (float*)d_out;
    float* ws  = (float*)d_ws;

    hipMemsetAsync(ws, 0, 24 * sizeof(float), stream);

    dim3 grid((A_N + 255) / 256, B_N);
    focal_main<<<grid, 256, 0, stream>>>(cls, regs, anchors, ann, ws);
    focal_final<<<1, 64, 0, stream>>>(ann, ws, out);
}

// Round 2
// 131.240 us; speedup vs baseline: 2.7227x; 2.7227x over previous
//
#include <hip/hip_runtime.h>

#define A_N 100000
#define B_N 8
#define C_N 80
#define M_N 32
#define FULL_BLOCKS 390   // 390*256 = 99840 anchors in full blocks

__device__ __forceinline__ float focal_elem(float pv, int m, int cidx) {
    float p = fminf(fmaxf(pv, 1e-4f), 1.f - 1e-4f);
    bool hit = (m == cidx);
    float q  = hit ? p : 1.f - p;        // log argument
    float om = hit ? 1.f - p : p;        // (..)^gamma base
    float f  = (hit ? 0.25f : 0.75f) * om * om;
    return f * (-__logf(q));
}

// ws layout (floats): [0..7] clsSum, [8..15] regSum, [16..23] numPos
template<bool FULL>
__global__ __launch_bounds__(256) void focal_main(
    const float* __restrict__ cls,     // [B,A,C]
    const float* __restrict__ regs,    // [B,A,4]
    const float* __restrict__ anchors, // [A,4]
    const float* __restrict__ ann,     // [B,M,5]
    float* __restrict__ ws)
{
    __shared__ float sAnn[M_N * 5];
    __shared__ int   sMeta[256];
    __shared__ float sRed[12];

    const int b   = blockIdx.y;
    const int s   = (FULL ? blockIdx.x : FULL_BLOCKS) * 256;
    const int tid = threadIdx.x;

    if (tid < M_N * 5) sAnn[tid] = ann[b * M_N * 5 + tid];
    __syncthreads();

    float regPart  = 0.f;
    float nposPart = 0.f;

    const int a = s + tid;
    int meta = -2;  // -2 = ignore/skip, -1 = negative, >=0 = positive class id
    if (FULL || a < A_N) {
        float4 an = reinterpret_cast<const float4*>(anchors)[a];
        float areaA = (an.z - an.x) * (an.w - an.y);
        float best = -1e30f;
        int bestIdx = 0;
        #pragma unroll
        for (int m = 0; m < M_N; ++m) {
            float gx1 = sAnn[m*5+0], gy1 = sAnn[m*5+1];
            float gx2 = sAnn[m*5+2], gy2 = sAnn[m*5+3];
            float gl  = sAnn[m*5+4];
            float iouv;
            if (gl >= 0.f) {
                float areaB = (gx2 - gx1) * (gy2 - gy1);
                float iw = fmaxf(fminf(an.z, gx2) - fmaxf(an.x, gx1), 0.f);
                float ih = fmaxf(fminf(an.w, gy2) - fmaxf(an.y, gy1), 0.f);
                float inter = iw * ih;
                float ua = fmaxf(areaA + areaB - inter, 1e-8f);
                iouv = inter / ua;
            } else {
                iouv = -1.f;
            }
            if (iouv > best) { best = iouv; bestIdx = m; }  // strict > == first-max argmax
        }
        bool pos = best >= 0.5f;
        bool neg = best <  0.4f;
        meta = pos ? (int)sAnn[bestIdx*5+4] : (neg ? -1 : -2);
        if (pos) {
            nposPart = 1.f;
            float4 rg = reinterpret_cast<const float4*>(regs)[(size_t)b * A_N + a];
            float gx1 = sAnn[bestIdx*5+0], gy1 = sAnn[bestIdx*5+1];
            float gx2 = sAnn[bestIdx*5+2], gy2 = sAnn[bestIdx*5+3];
            float aw = an.z - an.x, ah = an.w - an.y;
            float acx = an.x + 0.5f * aw, acy = an.y + 0.5f * ah;
            float gw0 = gx2 - gx1, gh0 = gy2 - gy1;
            float gcx = gx1 + 0.5f * gw0, gcy = gy1 + 0.5f * gh0;
            float gw = fmaxf(gw0, 1.f), gh = fmaxf(gh0, 1.f);
            float t0 = ((gcx - acx) / aw) * 10.f;
            float t1 = ((gcy - acy) / ah) * 10.f;
            float t2 = __logf(gw / aw) * 5.f;
            float t3 = __logf(gh / ah) * 5.f;
            float d0 = fabsf(t0 - rg.x), d1 = fabsf(t1 - rg.y);
            float d2 = fabsf(t2 - rg.z), d3 = fabsf(t3 - rg.w);
            #define SL1(d) ((d) <= (1.f/9.f) ? 4.5f*(d)*(d) : (d) - (0.5f/9.f))
            regPart = SL1(d0) + SL1(d1) + SL1(d2) + SL1(d3);
            #undef SL1
        }
    }
    sMeta[tid] = meta;
    __syncthreads();

    // ---- Phase B: stream [nAnch,80] cls slab, coalesced float4, unrolled for ILP
    const float4* cls4 = reinterpret_cast<const float4*>(cls + ((size_t)b * A_N + s) * C_N);
    float acc0 = 0.f, acc1 = 0.f, acc2 = 0.f, acc3 = 0.f;

    if (FULL) {
        #pragma unroll
        for (int k = 0; k < 20; ++k) {
            const int i = tid + (k << 8);
            float4 v = cls4[i];
            int al = i / 20;
            int cb = (i - al * 20) << 2;
            int m  = sMeta[al];
            float w = (m == -2) ? 0.f : 1.f;   // ignore band contributes nothing
            acc0 += w * focal_elem(v.x, m, cb + 0);
            acc1 += w * focal_elem(v.y, m, cb + 1);
            acc2 += w * focal_elem(v.z, m, cb + 2);
            acc3 += w * focal_elem(v.w, m, cb + 3);
        }
    } else {
        const int nAnch  = A_N - FULL_BLOCKS * 256;   // 160
        const int elems4 = nAnch * (C_N / 4);         // 3200
        for (int i = tid; i < elems4; i += 256) {
            float4 v = cls4[i];
            int al = i / 20;
            int cb = (i - al * 20) << 2;
            int m  = sMeta[al];
            float w = (m == -2) ? 0.f : 1.f;
            acc0 += w * focal_elem(v.x, m, cb + 0);
            acc1 += w * focal_elem(v.y, m, cb + 1);
            acc2 += w * focal_elem(v.z, m, cb + 2);
            acc3 += w * focal_elem(v.w, m, cb + 3);
        }
    }
    float clsPart = (acc0 + acc1) + (acc2 + acc3);

    // ---- wave reduce, then block reduce, 3 atomics per block
    #pragma unroll
    for (int off = 32; off > 0; off >>= 1) {
        clsPart  += __shfl_down(clsPart,  off);
        regPart  += __shfl_down(regPart,  off);
        nposPart += __shfl_down(nposPart, off);
    }
    const int wid = tid >> 6;
    if ((tid & 63) == 0) {
        sRed[wid]     = clsPart;
        sRed[4 + wid] = regPart;
        sRed[8 + wid] = nposPart;
    }
    __syncthreads();
    if (tid == 0) {
        float c = (sRed[0] + sRed[1]) + (sRed[2] + sRed[3]);
        float r = (sRed[4] + sRed[5]) + (sRed[6] + sRed[7]);
        float n = (sRed[8] + sRed[9]) + (sRed[10] + sRed[11]);
        atomicAdd(&ws[b],      c);
        atomicAdd(&ws[8 + b],  r);
        atomicAdd(&ws[16 + b], n);
    }
}

__global__ void focal_final(const float* __restrict__ ann,
                            const float* __restrict__ ws,
                            float* __restrict__ out)
{
    if (threadIdx.x == 0 && blockIdx.x == 0) {
        float cSum = 0.f, rSum = 0.f;
        for (int b = 0; b < B_N; ++b) {
            bool anyv = false;
            for (int m = 0; m < M_N; ++m)
                anyv = anyv || (ann[b * M_N * 5 + m * 5 + 4] >= 0.f);
            float np = ws[16 + b];
            float cl = ws[b] / fmaxf(np, 1.f);
            float rl = ws[8 + b] / fmaxf(4.f * np, 1.f);
            if (np <= 0.f) rl = 0.f;
            if (!anyv) { cl = 0.f; rl = 0.f; }
            cSum += cl;
            rSum += rl;
        }
        out[0] = cSum / (float)B_N;
        out[1] = rSum / (float)B_N;
    }
}

extern "C" void kernel_launch(void* const* d_in, const int* in_sizes, int n_in,
                              void* d_out, int out_size, void* d_ws, size_t ws_size,
                              hipStream_t stream) {
    const float* cls     = (const float*)d_in[0];
    const float* regs    = (const float*)d_in[1];
    const float* anchors = (const float*)d_in[2];
    const float* ann     = (const float*)d_in[3];
    float* out = (float*)d_out;
    float* ws  = (float*)d_ws;

    hipMemsetAsync(ws, 0, 24 * sizeof(float), stream);

    dim3 gridFull(FULL_BLOCKS, B_N);
    focal_main<true><<<gridFull, 256, 0, stream>>>(cls, regs, anchors, ann, ws);
    dim3 gridTail(1, B_N);
    focal_main<false><<<gridTail, 256, 0, stream>>>(cls, regs, anchors, ann, ws);
    focal_final<<<1, 64, 0, stream>>>(ann, ws, out);
}

// Round 3
// 124.874 us; speedup vs baseline: 2.8615x; 1.0510x over previous
//
#include <hip/hip_runtime.h>

#define A_N 100000
#define B_N 8
#define C_N 80
#define M_N 32

// ws layout (floats): [0..7] clsSum, [8..15] regSum, [16..23] numPos
__global__ __launch_bounds__(256) void focal_main(
    const float* __restrict__ cls,     // [B,A,C]
    const float* __restrict__ regs,    // [B,A,4]
    const float* __restrict__ anchors, // [A,4]
    const float* __restrict__ ann,     // [B,M,5]
    float* __restrict__ ws)
{
    __shared__ float sAnn[M_N * 5];
    __shared__ float sRed[12];

    const int b   = blockIdx.y;
    const int tid = threadIdx.x;
    const int a   = blockIdx.x * 256 + tid;

    if (tid < M_N * 5) sAnn[tid] = ann[b * M_N * 5 + tid];
    __syncthreads();

    float clsPart = 0.f, regPart = 0.f, nposPart = 0.f;

    if (a < A_N) {
        // ---- Phase A: IoU vs 32 GT (LDS broadcast reads), meta in register
        float4 an = reinterpret_cast<const float4*>(anchors)[a];
        float areaA = (an.z - an.x) * (an.w - an.y);
        float best = -1e30f;
        int bestIdx = 0;
        #pragma unroll
        for (int m = 0; m < M_N; ++m) {
            float gx1 = sAnn[m*5+0], gy1 = sAnn[m*5+1];
            float gx2 = sAnn[m*5+2], gy2 = sAnn[m*5+3];
            float gl  = sAnn[m*5+4];
            float iouv;
            if (gl >= 0.f) {
                float areaB = (gx2 - gx1) * (gy2 - gy1);
                float iw = fmaxf(fminf(an.z, gx2) - fmaxf(an.x, gx1), 0.f);
                float ih = fmaxf(fminf(an.w, gy2) - fmaxf(an.y, gy1), 0.f);
                float inter = iw * ih;
                float ua = fmaxf(areaA + areaB - inter, 1e-8f);
                iouv = inter / ua;
            } else {
                iouv = -1.f;
            }
            if (iouv > best) { best = iouv; bestIdx = m; }  // strict > == first-max argmax
        }
        bool pos = best >= 0.5f;
        bool neg = best <  0.4f;
        // meta: -2 ignore, -1 negative, >=0 positive class id
        const int meta = pos ? (int)sAnn[bestIdx*5+4] : (neg ? -1 : -2);

        // ---- regression (positives only; rare lanes)
        if (pos) {
            nposPart = 1.f;
            float4 rg = reinterpret_cast<const float4*>(regs)[(size_t)b * A_N + a];
            float gx1 = sAnn[bestIdx*5+0], gy1 = sAnn[bestIdx*5+1];
            float gx2 = sAnn[bestIdx*5+2], gy2 = sAnn[bestIdx*5+3];
            float aw = an.z - an.x, ah = an.w - an.y;
            float acx = an.x + 0.5f * aw, acy = an.y + 0.5f * ah;
            float gw0 = gx2 - gx1, gh0 = gy2 - gy1;
            float gcx = gx1 + 0.5f * gw0, gcy = gy1 + 0.5f * gh0;
            float gw = fmaxf(gw0, 1.f), gh = fmaxf(gh0, 1.f);
            float t0 = ((gcx - acx) / aw) * 10.f;
            float t1 = ((gcy - acy) / ah) * 10.f;
            float t2 = __logf(gw / aw) * 5.f;
            float t3 = __logf(gh / ah) * 5.f;
            float d0 = fabsf(t0 - rg.x), d1 = fabsf(t1 - rg.y);
            float d2 = fabsf(t2 - rg.z), d3 = fabsf(t3 - rg.w);
            #define SL1(d) ((d) <= (1.f/9.f) ? 4.5f*(d)*(d) : (d) - (0.5f/9.f))
            regPart = SL1(d0) + SL1(d1) + SL1(d2) + SL1(d3);
            #undef SL1
        }

        // ---- Phase B: this anchor's 80 classes: 20 float4 loads, one base,
        //      immediate offsets -> 20 independent loads in flight.
        const float4* p4 = reinterpret_cast<const float4*>(
            cls + ((size_t)b * A_N + a) * C_N);
        float4 v[20];
        #pragma unroll
        for (int k = 0; k < 20; ++k) v[k] = p4[k];

        // negative-style term for ALL classes; pick out p[class] on the fly
        float acc0 = 0.f, acc1 = 0.f, acc2 = 0.f, acc3 = 0.f;
        float pHit = 0.5f;
        #pragma unroll
        for (int k = 0; k < 20; ++k) {
            float pv[4] = {v[k].x, v[k].y, v[k].z, v[k].w};
            #pragma unroll
            for (int j = 0; j < 4; ++j) {
                float p  = fminf(fmaxf(pv[j], 1e-4f), 1.f - 1e-4f);
                float lg = __logf(1.f - p);
                float t  = p * p;
                if (j == 0) acc0 = fmaf(-t, lg, acc0);
                if (j == 1) acc1 = fmaf(-t, lg, acc1);
                if (j == 2) acc2 = fmaf(-t, lg, acc2);
                if (j == 3) acc3 = fmaf(-t, lg, acc3);
                if (4*k + j == meta) pHit = p;   // one cndmask; meta<0 never matches
            }
        }
        float wgt = (meta == -2) ? 0.f : 0.75f;
        clsPart = wgt * ((acc0 + acc1) + (acc2 + acc3));
        if (meta >= 0) {
            // swap neg-term -> hit-term at the assigned class
            float om = 1.f - pHit;
            clsPart += -0.25f * om * om * __logf(pHit)
                       + 0.75f * pHit * pHit * __logf(om);
        }
    }

    // ---- wave reduce, block reduce, 3 atomics per block
    #pragma unroll
    for (int off = 32; off > 0; off >>= 1) {
        clsPart  += __shfl_down(clsPart,  off);
        regPart  += __shfl_down(regPart,  off);
        nposPart += __shfl_down(nposPart, off);
    }
    const int wid = tid >> 6;
    if ((tid & 63) == 0) {
        sRed[wid]     = clsPart;
        sRed[4 + wid] = regPart;
        sRed[8 + wid] = nposPart;
    }
    __syncthreads();
    if (tid == 0) {
        float c = (sRed[0] + sRed[1]) + (sRed[2] + sRed[3]);
        float r = (sRed[4] + sRed[5]) + (sRed[6] + sRed[7]);
        float n = (sRed[8] + sRed[9]) + (sRed[10] + sRed[11]);
        atomicAdd(&ws[b],      c);
        atomicAdd(&ws[8 + b],  r);
        atomicAdd(&ws[16 + b], n);
    }
}

__global__ void focal_final(const float* __restrict__ ann,
                            const float* __restrict__ ws,
                            float* __restrict__ out)
{
    if (threadIdx.x == 0 && blockIdx.x == 0) {
        float cSum = 0.f, rSum = 0.f;
        for (int b = 0; b < B_N; ++b) {
            bool anyv = false;
            for (int m = 0; m < M_N; ++m)
                anyv = anyv || (ann[b * M_N * 5 + m * 5 + 4] >= 0.f);
            float np = ws[16 + b];
            float cl = ws[b] / fmaxf(np, 1.f);
            float rl = ws[8 + b] / fmaxf(4.f * np, 1.f);
            if (np <= 0.f) rl = 0.f;
            if (!anyv) { cl = 0.f; rl = 0.f; }
            cSum += cl;
            rSum += rl;
        }
        out[0] = cSum / (float)B_N;
        out[1] = rSum / (float)B_N;
    }
}

extern "C" void kernel_launch(void* const* d_in, const int* in_sizes, int n_in,
                              void* d_out, int out_size, void* d_ws, size_t ws_size,
                              hipStream_t stream) {
    const float* cls     = (const float*)d_in[0];
    const float* regs    = (const float*)d_in[1];
    const float* anchors = (const float*)d_in[2];
    const float* ann     = (const float*)d_in[3];
    float* out = (float*)d_out;
    float* ws  = (float*)d_ws;

    hipMemsetAsync(ws, 0, 24 * sizeof(float), stream);

    dim3 grid((A_N + 255) / 256, B_N);   // 391 x 8, last block partially idle
    focal_main<<<grid, 256, 0, stream>>>(cls, regs, anchors, ann, ws);
    focal_final<<<1, 64, 0, stream>>>(ann, ws, out);
}

// Round 4
// 108.092 us; speedup vs baseline: 3.3058x; 1.1553x over previous
//
#include <hip/hip_runtime.h>

#define A_N 100000
#define B_N 8
#define C_N 80
#define M_N 32
#define BLK 320                 // 5 waves; divisible by 20 (=C_N/4)
#define APB 320                 // anchors per block
#define NBLK 313                // ceil(100000/320)

// ws layout (floats): [0..7] clsSum, [8..15] regSum, [16..23] numPos
__global__ __launch_bounds__(BLK) void focal_main(
    const float* __restrict__ cls,     // [B,A,C]
    const float* __restrict__ regs,    // [B,A,4]
    const float* __restrict__ anchors, // [A,4]
    const float* __restrict__ ann,     // [B,M,5]
    float* __restrict__ ws)
{
    __shared__ float sAnn[M_N * 5];
    __shared__ int   sMeta[APB];
    __shared__ float sRed[15];

    const int b          = blockIdx.y;
    const int blockStart = blockIdx.x * APB;
    const int tid        = threadIdx.x;
    const int a          = blockStart + tid;

    if (tid < M_N * 5) sAnn[tid] = ann[b * M_N * 5 + tid];
    __syncthreads();

    float clsPart = 0.f, regPart = 0.f, nposPart = 0.f;
    float pHit = 0.5f;     // clamped p at assigned class (positives only)
    int   meta = -2;       // -2 ignore/invalid, -1 negative, >=0 positive class

    // ---- Phase A: one anchor per thread; meta -> LDS, reg-loss in register
    if (a < A_N) {
        float4 an = reinterpret_cast<const float4*>(anchors)[a];
        float areaA = (an.z - an.x) * (an.w - an.y);
        float best = -1e30f;
        int bestIdx = 0;
        #pragma unroll
        for (int m = 0; m < M_N; ++m) {
            float gx1 = sAnn[m*5+0], gy1 = sAnn[m*5+1];
            float gx2 = sAnn[m*5+2], gy2 = sAnn[m*5+3];
            float gl  = sAnn[m*5+4];
            float iouv;
            if (gl >= 0.f) {
                float areaB = (gx2 - gx1) * (gy2 - gy1);
                float iw = fmaxf(fminf(an.z, gx2) - fmaxf(an.x, gx1), 0.f);
                float ih = fmaxf(fminf(an.w, gy2) - fmaxf(an.y, gy1), 0.f);
                float inter = iw * ih;
                float ua = fmaxf(areaA + areaB - inter, 1e-8f);
                iouv = inter / ua;
            } else {
                iouv = -1.f;
            }
            if (iouv > best) { best = iouv; bestIdx = m; }  // strict > == first-max argmax
        }
        bool pos = best >= 0.5f;
        bool neg = best <  0.4f;
        meta = pos ? (int)sAnn[bestIdx*5+4] : (neg ? -1 : -2);

        if (pos) {
            nposPart = 1.f;
            // p at the assigned class (rare lanes -> one small gather)
            float ph = cls[((size_t)b * A_N + a) * C_N + meta];
            pHit = fminf(fmaxf(ph, 1e-4f), 1.f - 1e-4f);

            float4 rg = reinterpret_cast<const float4*>(regs)[(size_t)b * A_N + a];
            float gx1 = sAnn[bestIdx*5+0], gy1 = sAnn[bestIdx*5+1];
            float gx2 = sAnn[bestIdx*5+2], gy2 = sAnn[bestIdx*5+3];
            float aw = an.z - an.x, ah = an.w - an.y;
            float acx = an.x + 0.5f * aw, acy = an.y + 0.5f * ah;
            float gw0 = gx2 - gx1, gh0 = gy2 - gy1;
            float gcx = gx1 + 0.5f * gw0, gcy = gy1 + 0.5f * gh0;
            float gw = fmaxf(gw0, 1.f), gh = fmaxf(gh0, 1.f);
            float t0 = ((gcx - acx) / aw) * 10.f;
            float t1 = ((gcy - acy) / ah) * 10.f;
            float t2 = __logf(gw / aw) * 5.f;
            float t3 = __logf(gh / ah) * 5.f;
            float d0 = fabsf(t0 - rg.x), d1 = fabsf(t1 - rg.y);
            float d2 = fabsf(t2 - rg.z), d3 = fabsf(t3 - rg.w);
            #define SL1(d) ((d) <= (1.f/9.f) ? 4.5f*(d)*(d) : (d) - (0.5f/9.f))
            regPart = SL1(d0) + SL1(d1) + SL1(d2) + SL1(d3);
            #undef SL1
        }
    }
    sMeta[tid] = meta;
    __syncthreads();

    // ---- Phase B: stream the block's [320,80] slab.
    // thread t owns float4-column (t%20) and anchor-offset t/20; the k-loop
    // strides 320 float4s so the anchor index advances by 16 -> no per-iter
    // division, perfectly coalesced, one float4 live at a time.
    const int tD = tid / 20;            // computed once
    const float4* cls4 = reinterpret_cast<const float4*>(
        cls + ((size_t)b * A_N + blockStart) * C_N);

    #define ELEM4(v)                                               \
        float p0 = fminf(fmaxf((v).x, 1e-4f), 1.f - 1e-4f);        \
        float p1 = fminf(fmaxf((v).y, 1e-4f), 1.f - 1e-4f);        \
        float p2 = fminf(fmaxf((v).z, 1e-4f), 1.f - 1e-4f);        \
        float p3 = fminf(fmaxf((v).w, 1e-4f), 1.f - 1e-4f);        \
        float s4 = p0*p0*__logf(1.f-p0) + p1*p1*__logf(1.f-p1)     \
                 + p2*p2*__logf(1.f-p2) + p3*p3*__logf(1.f-p3);

    if (blockIdx.x != NBLK - 1) {       // uniform branch: full blocks
        #pragma unroll
        for (int k = 0; k < 20; ++k) {
            float4 v = cls4[k * BLK + tid];
            int   m  = sMeta[tD + (k << 4)];
            float w  = (m == -2) ? 0.f : 0.75f;
            ELEM4(v)
            clsPart = fmaf(-w, s4, clsPart);   // w * p^2 * (-log(1-p))
        }
    } else {                            // tail block: per-k guard
        #pragma unroll
        for (int k = 0; k < 20; ++k) {
            int al = tD + (k << 4);
            if (blockStart + al < A_N) {
                float4 v = cls4[k * BLK + tid];
                int   m  = sMeta[al];
                float w  = (m == -2) ? 0.f : 0.75f;
                ELEM4(v)
                clsPart = fmaf(-w, s4, clsPart);
            }
        }
    }
    #undef ELEM4

    // positive-anchor correction: replace neg-term with hit-term at class
    if (meta >= 0) {
        float om = 1.f - pHit;
        clsPart += -0.25f * om * om * __logf(pHit)
                   + 0.75f * pHit * pHit * __logf(om);
    }

    // ---- wave reduce (64), block reduce (5 waves), 3 atomics per block
    #pragma unroll
    for (int off = 32; off > 0; off >>= 1) {
        clsPart  += __shfl_down(clsPart,  off);
        regPart  += __shfl_down(regPart,  off);
        nposPart += __shfl_down(nposPart, off);
    }
    const int wid = tid >> 6;
    if ((tid & 63) == 0) {
        sRed[wid]      = clsPart;
        sRed[5 + wid]  = regPart;
        sRed[10 + wid] = nposPart;
    }
    __syncthreads();
    if (tid == 0) {
        float c = sRed[0] + sRed[1] + sRed[2] + sRed[3] + sRed[4];
        float r = sRed[5] + sRed[6] + sRed[7] + sRed[8] + sRed[9];
        float n = sRed[10] + sRed[11] + sRed[12] + sRed[13] + sRed[14];
        atomicAdd(&ws[b],      c);
        atomicAdd(&ws[8 + b],  r);
        atomicAdd(&ws[16 + b], n);
    }
}

__global__ void focal_final(const float* __restrict__ ann,
                            const float* __restrict__ ws,
                            float* __restrict__ out)
{
    if (threadIdx.x == 0 && blockIdx.x == 0) {
        float cSum = 0.f, rSum = 0.f;
        for (int b = 0; b < B_N; ++b) {
            bool anyv = false;
            for (int m = 0; m < M_N; ++m)
                anyv = anyv || (ann[b * M_N * 5 + m * 5 + 4] >= 0.f);
            float np = ws[16 + b];
            float cl = ws[b] / fmaxf(np, 1.f);
            float rl = ws[8 + b] / fmaxf(4.f * np, 1.f);
            if (np <= 0.f) rl = 0.f;
            if (!anyv) { cl = 0.f; rl = 0.f; }
            cSum += cl;
            rSum += rl;
        }
        out[0] = cSum / (float)B_N;
        out[1] = rSum / (float)B_N;
    }
}

extern "C" void kernel_launch(void* const* d_in, const int* in_sizes, int n_in,
                              void* d_out, int out_size, void* d_ws, size_t ws_size,
                              hipStream_t stream) {
    const float* cls     = (const float*)d_in[0];
    const float* regs    = (const float*)d_in[1];
    const float* anchors = (const float*)d_in[2];
    const float* ann     = (const float*)d_in[3];
    float* out = (float*)d_out;
    float* ws  = (float*)d_ws;

    hipMemsetAsync(ws, 0, 24 * sizeof(float), stream);

    dim3 grid(NBLK, B_N);
    focal_main<<<grid, BLK, 0, stream>>>(cls, regs, anchors, ann, ws);
    focal_final<<<1, 64, 0, stream>>>(ann, ws, out);
}

// Round 6
// 104.792 us; speedup vs baseline: 3.4099x; 1.0315x over previous
//
#include <hip/hip_runtime.h>

#define A_N 100000
#define B_N 8
#define C_N 80
#define M_N 32
#define BLK 320                 // 5 waves; divisible by 20 (=C_N/4)
#define APB 320                 // anchors per block
#define NBLK 313                // ceil(100000/320)

// weight * sum_j p^2 * log(1-p) accumulated negatively into acc
__device__ __forceinline__ void elem4(float4 v, float wgt, float& acc) {
    float p0 = fminf(fmaxf(v.x, 1e-4f), 1.f - 1e-4f);
    float p1 = fminf(fmaxf(v.y, 1e-4f), 1.f - 1e-4f);
    float p2 = fminf(fmaxf(v.z, 1e-4f), 1.f - 1e-4f);
    float p3 = fminf(fmaxf(v.w, 1e-4f), 1.f - 1e-4f);
    float s4 = p0*p0*__logf(1.f-p0) + p1*p1*__logf(1.f-p1)
             + p2*p2*__logf(1.f-p2) + p3*p3*__logf(1.f-p3);
    acc = fmaf(-wgt, s4, acc);
}

// ws layout (floats): [0..7] clsSum, [8..15] regSum, [16..23] numPos
__global__ __launch_bounds__(BLK) void focal_main(
    const float* __restrict__ cls,     // [B,A,C]
    const float* __restrict__ regs,    // [B,A,4]
    const float* __restrict__ anchors, // [A,4]
    const float* __restrict__ ann,     // [B,M,5]
    float* __restrict__ ws)
{
    __shared__ float sAnn[M_N * 5];
    __shared__ float sW[APB];          // 0.0 (ignore) or 0.75 per anchor
    __shared__ float sRed[15];

    const int b          = blockIdx.y;
    const int blockStart = blockIdx.x * APB;
    const int tid        = threadIdx.x;
    const int a          = blockStart + tid;

    if (tid < M_N * 5) sAnn[tid] = ann[b * M_N * 5 + tid];
    __syncthreads();

    float clsPart = 0.f, regPart = 0.f, nposPart = 0.f;
    float pHit = 0.5f;
    int   meta = -2;       // -2 ignore/invalid, -1 negative, >=0 positive class

    // ---- Phase A: one anchor per thread; weight -> LDS, reg-loss in register
    if (a < A_N) {
        float4 an = reinterpret_cast<const float4*>(anchors)[a];
        float areaA = (an.z - an.x) * (an.w - an.y);
        float best = -1e30f;
        int bestIdx = 0;
        #pragma unroll
        for (int m = 0; m < M_N; ++m) {
            float gx1 = sAnn[m*5+0], gy1 = sAnn[m*5+1];
            float gx2 = sAnn[m*5+2], gy2 = sAnn[m*5+3];
            float gl  = sAnn[m*5+4];
            float iouv;
            if (gl >= 0.f) {
                float areaB = (gx2 - gx1) * (gy2 - gy1);
                float iw = fmaxf(fminf(an.z, gx2) - fmaxf(an.x, gx1), 0.f);
                float ih = fmaxf(fminf(an.w, gy2) - fmaxf(an.y, gy1), 0.f);
                float inter = iw * ih;
                float ua = fmaxf(areaA + areaB - inter, 1e-8f);
                iouv = inter / ua;
            } else {
                iouv = -1.f;
            }
            if (iouv > best) { best = iouv; bestIdx = m; }  // strict > == first-max argmax
        }
        bool pos = best >= 0.5f;
        bool neg = best <  0.4f;
        meta = pos ? (int)sAnn[bestIdx*5+4] : (neg ? -1 : -2);

        if (pos) {
            nposPart = 1.f;
            float ph = cls[((size_t)b * A_N + a) * C_N + meta];
            pHit = fminf(fmaxf(ph, 1e-4f), 1.f - 1e-4f);

            float4 rg = reinterpret_cast<const float4*>(regs)[(size_t)b * A_N + a];
            float gx1 = sAnn[bestIdx*5+0], gy1 = sAnn[bestIdx*5+1];
            float gx2 = sAnn[bestIdx*5+2], gy2 = sAnn[bestIdx*5+3];
            float aw = an.z - an.x, ah = an.w - an.y;
            float acx = an.x + 0.5f * aw, acy = an.y + 0.5f * ah;
            float gw0 = gx2 - gx1, gh0 = gy2 - gy1;
            float gcx = gx1 + 0.5f * gw0, gcy = gy1 + 0.5f * gh0;
            float gw = fmaxf(gw0, 1.f), gh = fmaxf(gh0, 1.f);
            float t0 = ((gcx - acx) / aw) * 10.f;
            float t1 = ((gcy - acy) / ah) * 10.f;
            float t2 = __logf(gw / aw) * 5.f;
            float t3 = __logf(gh / ah) * 5.f;
            float d0 = fabsf(t0 - rg.x), d1 = fabsf(t1 - rg.y);
            float d2 = fabsf(t2 - rg.z), d3 = fabsf(t3 - rg.w);
            #define SL1(d) ((d) <= (1.f/9.f) ? 4.5f*(d)*(d) : (d) - (0.5f/9.f))
            regPart = SL1(d0) + SL1(d1) + SL1(d2) + SL1(d3);
            #undef SL1
        }
    }
    sW[tid] = (meta == -2) ? 0.f : 0.75f;
    __syncthreads();

    // ---- Phase B: stream the block's [320,80] slab, coalesced float4,
    //      4 independent loads clustered per iteration for BW saturation.
    const int tD = tid / 20;            // anchor offset of this thread's column
    const float4* cls4 = reinterpret_cast<const float4*>(
        cls + ((size_t)b * A_N + blockStart) * C_N);

    if (blockIdx.x != NBLK - 1) {       // uniform branch: full blocks
        #pragma unroll
        for (int k = 0; k < 20; k += 4) {
            // 4 independent loads issued before any use
            float4 v0 = cls4[(k + 0) * BLK + tid];
            float4 v1 = cls4[(k + 1) * BLK + tid];
            float4 v2 = cls4[(k + 2) * BLK + tid];
            float4 v3 = cls4[(k + 3) * BLK + tid];
            float w0 = sW[tD + ((k + 0) << 4)];
            float w1 = sW[tD + ((k + 1) << 4)];
            float w2 = sW[tD + ((k + 2) << 4)];
            float w3 = sW[tD + ((k + 3) << 4)];
            elem4(v0, w0, clsPart);
            elem4(v1, w1, clsPart);
            elem4(v2, w2, clsPart);
            elem4(v3, w3, clsPart);
        }
    } else {                            // tail block (160 anchors): per-k guard
        #pragma unroll
        for (int k = 0; k < 20; ++k) {
            int al = tD + (k << 4);
            if (blockStart + al < A_N) {
                float4 v = cls4[k * BLK + tid];
                elem4(v, sW[al], clsPart);
            }
        }
    }

    // positive-anchor correction: replace neg-term with hit-term at class
    if (meta >= 0) {
        float om = 1.f - pHit;
        clsPart += -0.25f * om * om * __logf(pHit)
                   + 0.75f * pHit * pHit * __logf(om);
    }

    // ---- wave reduce (64), block reduce (5 waves), 3 atomics per block
    #pragma unroll
    for (int off = 32; off > 0; off >>= 1) {
        clsPart  += __shfl_down(clsPart,  off);
        regPart  += __shfl_down(regPart,  off);
        nposPart += __shfl_down(nposPart, off);
    }
    const int wid = tid >> 6;
    if ((tid & 63) == 0) {
        sRed[wid]      = clsPart;
        sRed[5 + wid]  = regPart;
        sRed[10 + wid] = nposPart;
    }
    __syncthreads();
    if (tid == 0) {
        float c = sRed[0] + sRed[1] + sRed[2] + sRed[3] + sRed[4];
        float r = sRed[5] + sRed[6] + sRed[7] + sRed[8] + sRed[9];
        float n = sRed[10] + sRed[11] + sRed[12] + sRed[13] + sRed[14];
        atomicAdd(&ws[b],      c);
        atomicAdd(&ws[8 + b],  r);
        atomicAdd(&ws[16 + b], n);
    }
}

__global__ void focal_final(const float* __restrict__ ann,
                            const float* __restrict__ ws,
                            float* __restrict__ out)
{
    if (threadIdx.x == 0 && blockIdx.x == 0) {
        float cSum = 0.f, rSum = 0.f;
        for (int b = 0; b < B_N; ++b) {
            bool anyv = false;
            for (int m = 0; m < M_N; ++m)
                anyv = anyv || (ann[b * M_N * 5 + m * 5 + 4] >= 0.f);
            float np = ws[16 + b];
            float cl = ws[b] / fmaxf(np, 1.f);
            float rl = ws[8 + b] / fmaxf(4.f * np, 1.f);
            if (np <= 0.f) rl = 0.f;
            if (!anyv) { cl = 0.f; rl = 0.f; }
            cSum += cl;
            rSum += rl;
        }
        out[0] = cSum / (float)B_N;
        out[1] = rSum / (float)B_N;
    }
}

extern "C" void kernel_launch(void* const* d_in, const int* in_sizes, int n_in,
                              void* d_out, int out_size, void* d_ws, size_t ws_size,
                              hipStream_t stream) {
    const float* cls     = (const float*)d_in[0];
    const float* regs    = (const float*)d_in[1];
    const float* anchors = (const float*)d_in[2];
    const float* ann     = (const float*)d_in[3];
    float* out = (float*)d_out;
    float* ws  = (float*)d_ws;

    (void)hipMemsetAsync(ws, 0, 24 * sizeof(float), stream);

    dim3 grid(NBLK, B_N);
    focal_main<<<grid, BLK, 0, stream>>>(cls, regs, anchors, ann, ws);
    focal_final<<<1, 64, 0, stream>>>(ann, ws, out);
}